// Round 1
// baseline (193.617 us; speedup 1.0000x reference)
//
#include <hip/hip_runtime.h>
#include <cstdint>
#include <cstddef>

static constexpr int C = 256;
static constexpr int N = 1024;
static constexpr int M = 4;                     // T*B
static constexpr size_t PLANE = (size_t)M * C * N;  // 1048576 elements per branch

// ---------------------------------------------------------------------------
// GEMM: H[m][o][n] = sum_c W[o][c] * X[m][c][n], fp64 accumulate, fp64 out.
// Fused over the 3 branches (q from x; k,v from y). Tile 64x64, K-chunk 64.
// ---------------------------------------------------------------------------
__global__ __launch_bounds__(256) void gemm_qkv_kernel(
    const float* __restrict__ x, const float* __restrict__ y,
    const float* __restrict__ Wq, const float* __restrict__ Wk, const float* __restrict__ Wv,
    double* __restrict__ hq, double* __restrict__ hk, double* __restrict__ hv)
{
    const int bz = blockIdx.z;       // 0..11
    const int br = bz >> 2;          // 0=q,1=k,2=v
    const int m  = bz & 3;
    const float* __restrict__ W = (br == 0) ? Wq : (br == 1) ? Wk : Wv;
    const float* __restrict__ X = ((br == 0) ? x : y) + (size_t)m * C * N;
    double* __restrict__ H = ((br == 0) ? hq : (br == 1) ? hk : hv) + (size_t)m * C * N;

    const int n0 = blockIdx.x * 64;
    const int o0 = blockIdx.y * 64;
    const int tid = threadIdx.x;
    const int tx = tid & 15;         // n sub-tile (4 cols each)
    const int ty = tid >> 4;         // o sub-tile (4 rows each)

    __shared__ double Ws[64][66];    // [o][c], pad to dodge stride conflicts
    __shared__ double Xs[64][66];    // [c][n]

    double acc[4][4];
    #pragma unroll
    for (int i = 0; i < 4; ++i) {
        #pragma unroll
        for (int j = 0; j < 4; ++j) acc[i][j] = 0.0;
    }

    for (int c0 = 0; c0 < C; c0 += 64) {
        #pragma unroll
        for (int t = 0; t < 16; ++t) {
            int l = t * 256 + tid;
            int r = l >> 6, cc = l & 63;
            Ws[r][cc] = (double)W[(o0 + r) * C + (c0 + cc)];
            Xs[r][cc] = (double)X[(size_t)(c0 + r) * N + (n0 + cc)];
        }
        __syncthreads();
        #pragma unroll 8
        for (int kk = 0; kk < 64; ++kk) {
            double wv[4], xv[4];
            #pragma unroll
            for (int i = 0; i < 4; ++i) wv[i] = Ws[ty * 4 + i][kk];
            #pragma unroll
            for (int j = 0; j < 4; ++j) xv[j] = Xs[kk][tx * 4 + j];
            #pragma unroll
            for (int i = 0; i < 4; ++i) {
                #pragma unroll
                for (int j = 0; j < 4; ++j) acc[i][j] += wv[i] * xv[j];
            }
        }
        __syncthreads();
    }
    #pragma unroll
    for (int i = 0; i < 4; ++i) {
        #pragma unroll
        for (int j = 0; j < 4; ++j)
            H[(size_t)(o0 + ty * 4 + i) * N + (n0 + tx * 4 + j)] = acc[i][j];
    }
}

// Proj GEMM: same structure, binary uint8 input.
__global__ __launch_bounds__(256) void gemm_p_kernel(
    const float* __restrict__ Wp, const unsigned char* __restrict__ s2,
    double* __restrict__ hp)
{
    const int m = blockIdx.z;
    const unsigned char* __restrict__ X = s2 + (size_t)m * C * N;
    double* __restrict__ H = hp + (size_t)m * C * N;

    const int n0 = blockIdx.x * 64;
    const int o0 = blockIdx.y * 64;
    const int tid = threadIdx.x;
    const int tx = tid & 15;
    const int ty = tid >> 4;

    __shared__ double Ws[64][66];
    __shared__ double Xs[64][66];

    double acc[4][4];
    #pragma unroll
    for (int i = 0; i < 4; ++i) {
        #pragma unroll
        for (int j = 0; j < 4; ++j) acc[i][j] = 0.0;
    }

    for (int c0 = 0; c0 < C; c0 += 64) {
        #pragma unroll
        for (int t = 0; t < 16; ++t) {
            int l = t * 256 + tid;
            int r = l >> 6, cc = l & 63;
            Ws[r][cc] = (double)Wp[(o0 + r) * C + (c0 + cc)];
            Xs[r][cc] = (double)X[(size_t)(c0 + r) * N + (n0 + cc)];
        }
        __syncthreads();
        #pragma unroll 8
        for (int kk = 0; kk < 64; ++kk) {
            double wv[4], xv[4];
            #pragma unroll
            for (int i = 0; i < 4; ++i) wv[i] = Ws[ty * 4 + i][kk];
            #pragma unroll
            for (int j = 0; j < 4; ++j) xv[j] = Xs[kk][tx * 4 + j];
            #pragma unroll
            for (int i = 0; i < 4; ++i) {
                #pragma unroll
                for (int j = 0; j < 4; ++j) acc[i][j] += wv[i] * xv[j];
            }
        }
        __syncthreads();
    }
    #pragma unroll
    for (int i = 0; i < 4; ++i) {
        #pragma unroll
        for (int j = 0; j < 4; ++j)
            H[(size_t)(o0 + ty * 4 + i) * N + (n0 + tx * 4 + j)] = acc[i][j];
    }
}

// ---------------------------------------------------------------------------
// BatchNorm statistics: per (branch, channel) mean & 1/sqrt(var+eps) over the
// 4096 values (m,n). fp64 throughout. grid=(256, nBranches).
// ---------------------------------------------------------------------------
__global__ __launch_bounds__(256) void bn_stats_kernel(
    const double* __restrict__ hbase, double* __restrict__ stats)
{
    const int o  = blockIdx.x;
    const int br = blockIdx.y;
    const double* __restrict__ h = hbase + (size_t)br * PLANE;
    const int tid = threadIdx.x;

    double s = 0.0, ss = 0.0;
    #pragma unroll
    for (int j = 0; j < 16; ++j) {
        int l = j * 256 + tid;              // 0..4095
        int mm = l >> 10, nn = l & 1023;
        double v = h[(size_t)mm * C * N + (size_t)o * N + nn];
        s += v; ss += v * v;
    }
    #pragma unroll
    for (int off = 32; off > 0; off >>= 1) {
        s  += __shfl_down(s, off, 64);
        ss += __shfl_down(ss, off, 64);
    }
    __shared__ double rs[4], rss[4];
    int lane = tid & 63, w = tid >> 6;
    if (lane == 0) { rs[w] = s; rss[w] = ss; }
    __syncthreads();
    if (tid == 0) {
        double S  = rs[0] + rs[1] + rs[2] + rs[3];
        double SS = rss[0] + rss[1] + rss[2] + rss[3];
        double mean = S / 4096.0;
        double var  = SS / 4096.0 - mean * mean;
        stats[(size_t)(br * C + o) * 2 + 0] = mean;
        stats[(size_t)(br * C + o) * 2 + 1] = 1.0 / sqrt(var + 1e-5);
    }
}

// ---------------------------------------------------------------------------
// Spike for q/k/v: binary = (gamma*(h-mean)*invstd + beta >= 1.0)
// ---------------------------------------------------------------------------
__global__ __launch_bounds__(256) void spike_qkv_kernel(
    const double* __restrict__ hbase, const double* __restrict__ stats,
    const float* __restrict__ gq, const float* __restrict__ bq,
    const float* __restrict__ gk, const float* __restrict__ bk,
    const float* __restrict__ gv, const float* __restrict__ bv,
    unsigned char* __restrict__ sbase)
{
    const int br = blockIdx.y;
    const float* g = (br == 0) ? gq : (br == 1) ? gk : gv;
    const float* b = (br == 0) ? bq : (br == 1) ? bk : bv;
    const size_t idx = (size_t)blockIdx.x * 256 + threadIdx.x;  // < PLANE
    const int c = (int)((idx >> 10) & 255);
    const double mean = stats[(size_t)(br * C + c) * 2 + 0];
    const double inv  = stats[(size_t)(br * C + c) * 2 + 1];
    const double t = (double)g[c] * (hbase[(size_t)br * PLANE + idx] - mean) * inv + (double)b[c];
    sbase[(size_t)br * PLANE + idx] = (t >= 1.0) ? (unsigned char)1 : (unsigned char)0;
}

// ---------------------------------------------------------------------------
// kTv[t][h][d][dp] = sum_n k[t, h*16+d, n] * v[t, h*16+dp, n]  (exact integers)
// Bytes are 0/1, so per 4-byte word: popc(kw & vw).
// ---------------------------------------------------------------------------
__global__ __launch_bounds__(256) void ktv_kernel(
    const unsigned char* __restrict__ kb, const unsigned char* __restrict__ vb,
    int* __restrict__ ktv)
{
    const int t  = blockIdx.x >> 4;
    const int hh = blockIdx.x & 15;
    const int tid = threadIdx.x;
    __shared__ unsigned int kw[16][257];
    __shared__ unsigned int vw[16][257];
    #pragma unroll
    for (int j = 0; j < 16; ++j) {
        int l = j * 256 + tid;              // 0..4095
        int r = l >> 8, w = l & 255;
        size_t goff = ((size_t)t * C + hh * 16 + r) * N + (size_t)w * 4;
        kw[r][w] = *(const unsigned int*)(kb + goff);
        vw[r][w] = *(const unsigned int*)(vb + goff);
    }
    __syncthreads();
    const int d = tid >> 4, dp = tid & 15;
    int sum = 0;
    for (int w = 0; w < 256; ++w)
        sum += __popc(kw[d][w] & vw[dp][w]);
    ktv[(size_t)blockIdx.x * 256 + tid] = sum;   // tid == d*16+dp
}

// ---------------------------------------------------------------------------
// s2[t, h*16+dp, n] = ( sum_d q[t,h*16+d,n] * kTv[d][dp] ) >= 2   (== 0.25*S>=0.5)
// ---------------------------------------------------------------------------
__global__ __launch_bounds__(256) void s2_kernel(
    const unsigned char* __restrict__ qb, const int* __restrict__ ktv,
    unsigned char* __restrict__ s2)
{
    const int t = blockIdx.z, hh = blockIdx.y;
    const int tid = threadIdx.x;
    __shared__ int kt[256];
    kt[tid] = ktv[(size_t)(t * 16 + hh) * 256 + tid];
    __syncthreads();
    const int n = blockIdx.x * 256 + tid;
    int sums[16];
    #pragma unroll
    for (int dp = 0; dp < 16; ++dp) sums[dp] = 0;
    #pragma unroll
    for (int d = 0; d < 16; ++d) {
        int qv = (int)qb[((size_t)t * C + hh * 16 + d) * N + n];
        #pragma unroll
        for (int dp = 0; dp < 16; ++dp)
            sums[dp] += qv * kt[d * 16 + dp];
    }
    #pragma unroll
    for (int dp = 0; dp < 16; ++dp)
        s2[((size_t)t * C + hh * 16 + dp) * N + n] = (sums[dp] >= 2) ? 1 : 0;
}

// ---------------------------------------------------------------------------
// Final spike -> fp32 0/1 output
// ---------------------------------------------------------------------------
__global__ __launch_bounds__(256) void spike_final_kernel(
    const double* __restrict__ hp, const double* __restrict__ stats,
    const float* __restrict__ gp, const float* __restrict__ bp,
    float* __restrict__ out)
{
    const size_t idx = (size_t)blockIdx.x * 256 + threadIdx.x;
    const int c = (int)((idx >> 10) & 255);
    const double mean = stats[(size_t)c * 2 + 0];
    const double inv  = stats[(size_t)c * 2 + 1];
    const double t = (double)gp[c] * (hp[idx] - mean) * inv + (double)bp[c];
    out[idx] = (t >= 1.0) ? 1.0f : 0.0f;
}

// ---------------------------------------------------------------------------
extern "C" void kernel_launch(void* const* d_in, const int* in_sizes, int n_in,
                              void* d_out, int out_size, void* d_ws, size_t ws_size,
                              hipStream_t stream)
{
    const float* x  = (const float*)d_in[0];
    const float* y  = (const float*)d_in[1];
    const float* Wq = (const float*)d_in[2];
    const float* gq = (const float*)d_in[3];
    const float* bq = (const float*)d_in[4];
    const float* Wk = (const float*)d_in[5];
    const float* gk = (const float*)d_in[6];
    const float* bk = (const float*)d_in[7];
    const float* Wv = (const float*)d_in[8];
    const float* gv = (const float*)d_in[9];
    const float* bv = (const float*)d_in[10];
    const float* Wp = (const float*)d_in[11];
    const float* gp = (const float*)d_in[12];
    const float* bp = (const float*)d_in[13];
    float* out = (float*)d_out;

    // Workspace layout (total ~36.1 MB):
    char* ws = (char*)d_ws;
    double* hq = (double*)(ws);                          // 3 x 8MB (hq,hk,hv contiguous)
    double* hk = hq + PLANE;
    double* hv = hq + 2 * PLANE;
    double* hp = (double*)(ws + 3 * PLANE * sizeof(double));   // 8MB
    unsigned char* qb  = (unsigned char*)(ws + 4 * PLANE * sizeof(double)); // 4 x 1MB
    unsigned char* kb2 = qb + PLANE;
    unsigned char* vb2 = qb + 2 * PLANE;
    unsigned char* s2b = qb + 3 * PLANE;
    int*    ktvp  = (int*)(ws + 4 * PLANE * sizeof(double) + 4 * PLANE);     // 64KB
    double* stats = (double*)(ws + 4 * PLANE * sizeof(double) + 4 * PLANE + 65536); // 12KB
    double* statp = stats + 3 * (size_t)C * 2;                                // 4KB

    gemm_qkv_kernel<<<dim3(16, 4, 12), 256, 0, stream>>>(x, y, Wq, Wk, Wv, hq, hk, hv);
    bn_stats_kernel<<<dim3(256, 3), 256, 0, stream>>>(hq, stats);
    spike_qkv_kernel<<<dim3(4096, 3), 256, 0, stream>>>(hq, stats, gq, bq, gk, bk, gv, bv, qb);
    ktv_kernel<<<dim3(64), 256, 0, stream>>>(kb2, vb2, ktvp);
    s2_kernel<<<dim3(4, 16, 4), 256, 0, stream>>>(qb, ktvp, s2b);
    gemm_p_kernel<<<dim3(16, 4, 4), 256, 0, stream>>>(Wp, s2b, hp);
    bn_stats_kernel<<<dim3(256, 1), 256, 0, stream>>>(hp, statp);
    spike_final_kernel<<<dim3(4096), 256, 0, stream>>>(hp, statp, gp, bp, out);
}

// Round 3
// 182.487 us; speedup vs baseline: 1.0610x; 1.0610x over previous
//
#include <hip/hip_runtime.h>
#include <cstdint>
#include <cstddef>

static constexpr int C = 256;
static constexpr int N = 1024;
static constexpr int M = 4;                         // T*B
static constexpr size_t PLANE = (size_t)M * C * N;  // 1M elements per branch

// ---------------------------------------------------------------------------
// Prologue: convert the four 256x256 fp32 weight matrices to fp64 (same [o][c]
// layout). grid = 256 blocks x 256 threads; each thread writes one element of
// each matrix.
// ---------------------------------------------------------------------------
__global__ __launch_bounds__(256) void wconv_kernel(
    const float* __restrict__ Wq, const float* __restrict__ Wk,
    const float* __restrict__ Wv, const float* __restrict__ Wp,
    double* __restrict__ W64)
{
    const int idx = blockIdx.x * 256 + threadIdx.x;   // 0..65535
    W64[(size_t)0 * 65536 + idx] = (double)Wq[idx];
    W64[(size_t)1 * 65536 + idx] = (double)Wk[idx];
    W64[(size_t)2 * 65536 + idx] = (double)Wv[idx];
    W64[(size_t)3 * 65536 + idx] = (double)Wp[idx];
}

// ---------------------------------------------------------------------------
// fp64 GEMM, LDS-free: H[m][o][n] = sum_c W[o][c] * X[m][c][n].
// Wave = 8 o-rows x 64 n (n = lane). X loads coalesced; W loads wave-uniform
// (broadcast). grid = (16 n-tiles, 8 o-tiles, 12 planes br*4+m), 256 threads.
// ---------------------------------------------------------------------------
__global__ __launch_bounds__(256, 4) void gemm_qkv(
    const float* __restrict__ x, const float* __restrict__ y,
    const double* __restrict__ W64, double* __restrict__ hbase)
{
    const int bz = blockIdx.z;
    const int br = bz >> 2, m = bz & 3;
    const float* __restrict__ X = ((br == 0) ? x : y) + (size_t)m * C * N;
    const double* __restrict__ W = W64 + (size_t)br * C * C;
    double* __restrict__ H = hbase + (size_t)br * PLANE + (size_t)m * C * N;

    const int lane = threadIdx.x & 63;
    const int wv = __builtin_amdgcn_readfirstlane(threadIdx.x >> 6);
    const int o0 = blockIdx.y * 32 + wv * 8;
    const int n  = blockIdx.x * 64 + lane;

    const float*  __restrict__ Xn = X + n;
    const double* __restrict__ Wo = W + (size_t)o0 * C;

    double acc[8];
    #pragma unroll
    for (int i = 0; i < 8; ++i) acc[i] = 0.0;

    for (int k = 0; k < C; k += 4) {
        double xv[4];
        #pragma unroll
        for (int j = 0; j < 4; ++j)
            xv[j] = (double)Xn[(size_t)(k + j) * N];
        #pragma unroll
        for (int i = 0; i < 8; ++i) {
            const double* __restrict__ wr = Wo + (size_t)i * C + k;
            acc[i] = fma(wr[0], xv[0], acc[i]);
            acc[i] = fma(wr[1], xv[1], acc[i]);
            acc[i] = fma(wr[2], xv[2], acc[i]);
            acc[i] = fma(wr[3], xv[3], acc[i]);
        }
    }
    #pragma unroll
    for (int i = 0; i < 8; ++i)
        H[(size_t)(o0 + i) * N + n] = acc[i];
}

// Proj GEMM: same structure, binary uint8 X. grid = (16, 8, 4 planes).
__global__ __launch_bounds__(256, 4) void gemm_p(
    const unsigned char* __restrict__ s2, const double* __restrict__ W64,
    double* __restrict__ hp)
{
    const int m = blockIdx.z;
    const unsigned char* __restrict__ X = s2 + (size_t)m * C * N;
    const double* __restrict__ W = W64 + (size_t)3 * C * C;   // Wp
    double* __restrict__ H = hp + (size_t)m * C * N;

    const int lane = threadIdx.x & 63;
    const int wv = __builtin_amdgcn_readfirstlane(threadIdx.x >> 6);
    const int o0 = blockIdx.y * 32 + wv * 8;
    const int n  = blockIdx.x * 64 + lane;

    const unsigned char* __restrict__ Xn = X + n;
    const double* __restrict__ Wo = W + (size_t)o0 * C;

    double acc[8];
    #pragma unroll
    for (int i = 0; i < 8; ++i) acc[i] = 0.0;

    for (int k = 0; k < C; k += 4) {
        double xv[4];
        #pragma unroll
        for (int j = 0; j < 4; ++j)
            xv[j] = (double)(int)Xn[(size_t)(k + j) * N];
        #pragma unroll
        for (int i = 0; i < 8; ++i) {
            const double* __restrict__ wr = Wo + (size_t)i * C + k;
            acc[i] = fma(wr[0], xv[0], acc[i]);
            acc[i] = fma(wr[1], xv[1], acc[i]);
            acc[i] = fma(wr[2], xv[2], acc[i]);
            acc[i] = fma(wr[3], xv[3], acc[i]);
        }
    }
    #pragma unroll
    for (int i = 0; i < 8; ++i)
        H[(size_t)(o0 + i) * N + n] = acc[i];
}

// ---------------------------------------------------------------------------
// Fused BN stats + spike for q/k/v. Block = (channel o, branch br).
// Values held in registers: single read of h. Writes 0/1 bytes.
// ---------------------------------------------------------------------------
__global__ __launch_bounds__(256) void bnspike_qkv(
    const double* __restrict__ hbase,
    const float* __restrict__ gq, const float* __restrict__ bq,
    const float* __restrict__ gk, const float* __restrict__ bk,
    const float* __restrict__ gv, const float* __restrict__ bv,
    unsigned char* __restrict__ sbase)
{
    const int o  = blockIdx.x;
    const int br = blockIdx.y;
    const double* __restrict__ h = hbase + (size_t)br * PLANE + (size_t)o * N;
    const int tid = threadIdx.x;

    double v[16];
    double s = 0.0, ss = 0.0;
    #pragma unroll
    for (int j = 0; j < 16; ++j) {
        int l  = j * 256 + tid;             // 0..4095
        int mm = l >> 10, nn = l & 1023;
        v[j] = h[(size_t)mm * C * N + nn];
        s += v[j]; ss += v[j] * v[j];
    }
    #pragma unroll
    for (int off = 32; off > 0; off >>= 1) {
        s  += __shfl_down(s, off, 64);
        ss += __shfl_down(ss, off, 64);
    }
    __shared__ double rs[4], rss[4], sstat[2];
    const int lane = tid & 63, wv_ = tid >> 6;
    if (lane == 0) { rs[wv_] = s; rss[wv_] = ss; }
    __syncthreads();
    if (tid == 0) {
        double S  = rs[0] + rs[1] + rs[2] + rs[3];
        double SS = rss[0] + rss[1] + rss[2] + rss[3];
        double mean = S / 4096.0;
        double var  = SS / 4096.0 - mean * mean;
        sstat[0] = mean;
        sstat[1] = 1.0 / sqrt(var + 1e-5);
    }
    __syncthreads();
    const double mean = sstat[0], inv = sstat[1];
    const float* g = (br == 0) ? gq : (br == 1) ? gk : gv;
    const float* b = (br == 0) ? bq : (br == 1) ? bk : bv;
    const double gc = (double)g[o], bc = (double)b[o];
    unsigned char* out = sbase + (size_t)br * PLANE + (size_t)o * N;
    #pragma unroll
    for (int j = 0; j < 16; ++j) {
        int l  = j * 256 + tid;
        int mm = l >> 10, nn = l & 1023;
        double t = gc * (v[j] - mean) * inv + bc;
        out[(size_t)mm * C * N + nn] = (t >= 1.0) ? (unsigned char)1 : (unsigned char)0;
    }
}

// ---------------------------------------------------------------------------
// Fused attention: kTv (popc over packed 0/1 bytes) + S = q . kTv, spike S>=2
// (== SCALE*S >= 0.5 with exact integers). grid = (4 n-chunks, 16 heads, 4 t).
// ---------------------------------------------------------------------------
__global__ __launch_bounds__(256) void attn_kernel(
    const unsigned char* __restrict__ qb, const unsigned char* __restrict__ kb,
    const unsigned char* __restrict__ vb, unsigned char* __restrict__ s2)
{
    const int nc = blockIdx.x;
    const int hh = blockIdx.y;
    const int t  = blockIdx.z;
    const int tid = threadIdx.x;

    __shared__ unsigned int kw[16][257];
    __shared__ unsigned int vw[16][257];
    __shared__ int kt[256];

    #pragma unroll
    for (int j = 0; j < 4; ++j) {
        int idx = j * 256 + tid;            // 0..1023 -> 16 rows x 64 uint4
        int r = idx >> 6, q4 = idx & 63;
        size_t goff = ((size_t)(t * C + hh * 16 + r)) * N + (size_t)q4 * 16;
        uint4 kk = *(const uint4*)(kb + goff);
        uint4 vv = *(const uint4*)(vb + goff);
        kw[r][q4 * 4 + 0] = kk.x; kw[r][q4 * 4 + 1] = kk.y;
        kw[r][q4 * 4 + 2] = kk.z; kw[r][q4 * 4 + 3] = kk.w;
        vw[r][q4 * 4 + 0] = vv.x; vw[r][q4 * 4 + 1] = vv.y;
        vw[r][q4 * 4 + 2] = vv.z; vw[r][q4 * 4 + 3] = vv.w;
    }
    __syncthreads();

    const int d = tid >> 4, dp = tid & 15;
    int sum = 0;
    #pragma unroll 8
    for (int wd = 0; wd < 256; ++wd)
        sum += __popc(kw[d][wd] & vw[dp][wd]);
    kt[tid] = sum;                          // kt[d*16+dp], exact integer
    __syncthreads();

    const int n = nc * 256 + tid;
    int sums[16];
    #pragma unroll
    for (int i = 0; i < 16; ++i) sums[i] = 0;
    #pragma unroll
    for (int d2 = 0; d2 < 16; ++d2) {
        int qv = (int)qb[((size_t)(t * C + hh * 16 + d2)) * N + n];
        #pragma unroll
        for (int dp2 = 0; dp2 < 16; ++dp2)
            sums[dp2] += qv * kt[d2 * 16 + dp2];
    }
    #pragma unroll
    for (int dp2 = 0; dp2 < 16; ++dp2)
        s2[((size_t)(t * C + hh * 16 + dp2)) * N + n] = (sums[dp2] >= 2) ? 1 : 0;
}

// ---------------------------------------------------------------------------
// Fused BN stats + spike for proj -> fp32 0/1 output. grid = (256)
// ---------------------------------------------------------------------------
__global__ __launch_bounds__(256) void bnspike_p(
    const double* __restrict__ hp,
    const float* __restrict__ gp, const float* __restrict__ bp,
    float* __restrict__ outp)
{
    const int o = blockIdx.x;
    const double* __restrict__ h = hp + (size_t)o * N;
    const int tid = threadIdx.x;

    double v[16];
    double s = 0.0, ss = 0.0;
    #pragma unroll
    for (int j = 0; j < 16; ++j) {
        int l  = j * 256 + tid;
        int mm = l >> 10, nn = l & 1023;
        v[j] = h[(size_t)mm * C * N + nn];
        s += v[j]; ss += v[j] * v[j];
    }
    #pragma unroll
    for (int off = 32; off > 0; off >>= 1) {
        s  += __shfl_down(s, off, 64);
        ss += __shfl_down(ss, off, 64);
    }
    __shared__ double rs[4], rss[4], sstat[2];
    const int lane = tid & 63, wv_ = tid >> 6;
    if (lane == 0) { rs[wv_] = s; rss[wv_] = ss; }
    __syncthreads();
    if (tid == 0) {
        double S  = rs[0] + rs[1] + rs[2] + rs[3];
        double SS = rss[0] + rss[1] + rss[2] + rss[3];
        double mean = S / 4096.0;
        double var  = SS / 4096.0 - mean * mean;
        sstat[0] = mean;
        sstat[1] = 1.0 / sqrt(var + 1e-5);
    }
    __syncthreads();
    const double mean = sstat[0], inv = sstat[1];
    const double gc = (double)gp[o], bc = (double)bp[o];
    float* out = outp + (size_t)o * N;
    #pragma unroll
    for (int j = 0; j < 16; ++j) {
        int l  = j * 256 + tid;
        int mm = l >> 10, nn = l & 1023;
        double t = gc * (v[j] - mean) * inv + bc;
        out[(size_t)mm * C * N + nn] = (t >= 1.0) ? 1.0f : 0.0f;
    }
}

// ---------------------------------------------------------------------------
extern "C" void kernel_launch(void* const* d_in, const int* in_sizes, int n_in,
                              void* d_out, int out_size, void* d_ws, size_t ws_size,
                              hipStream_t stream)
{
    const float* x  = (const float*)d_in[0];
    const float* y  = (const float*)d_in[1];
    const float* Wq = (const float*)d_in[2];
    const float* gq = (const float*)d_in[3];
    const float* bq = (const float*)d_in[4];
    const float* Wk = (const float*)d_in[5];
    const float* gk = (const float*)d_in[6];
    const float* bk = (const float*)d_in[7];
    const float* Wv = (const float*)d_in[8];
    const float* gv = (const float*)d_in[9];
    const float* bv = (const float*)d_in[10];
    const float* Wp = (const float*)d_in[11];
    const float* gp = (const float*)d_in[12];
    const float* bp = (const float*)d_in[13];
    float* out = (float*)d_out;

    // Workspace layout (30 MB total):
    //   [0, 2MB)   W64 (4 matrices, fp64)
    //   [2, 26MB)  hq (3 branches fp64) ; hp (4 planes fp64) aliases [2,10MB)
    //   [26, 30MB) qb/kb/vb/s2b binary bytes
    char* ws = (char*)d_ws;
    double* W64 = (double*)ws;
    double* hq  = (double*)(ws + (size_t)4 * 65536 * 8);
    double* hp  = hq;                                      // alias: hq dead by then
    unsigned char* qb  = (unsigned char*)(ws + (size_t)4 * 65536 * 8 + 3 * PLANE * 8);
    unsigned char* kb2 = qb + PLANE;
    unsigned char* vb2 = qb + 2 * PLANE;
    unsigned char* s2b = qb + 3 * PLANE;

    wconv_kernel<<<dim3(256), 256, 0, stream>>>(Wq, Wk, Wv, Wp, W64);
    gemm_qkv<<<dim3(16, 8, 12), 256, 0, stream>>>(x, y, W64, hq);
    bnspike_qkv<<<dim3(256, 3), 256, 0, stream>>>(hq, gq, bq, gk, bk, gv, bv, qb);
    attn_kernel<<<dim3(4, 16, 4), 256, 0, stream>>>(qb, kb2, vb2, s2b);
    gemm_p<<<dim3(16, 8, 4), 256, 0, stream>>>(s2b, W64, hp);
    bnspike_p<<<dim3(256), 256, 0, stream>>>(hp, gp, bp, out);
}